// Round 15
// baseline (58.428 us; speedup 1.0000x reference)
//
#include <hip/hip_runtime.h>
#include <hip/hip_bf16.h>

#define B_ 32
#define T_ 256
#define NIN_ 128
#define H_ 32
#define NOUT_ 128
#define R_ (B_ * T_)   // 8192 rows

#define C2L2E 2.88539008177792681472f   // 2*log2(e)
#define L2E   1.44269504088896341f
#define LN2   0.69314718055994531f

__device__ __forceinline__ float rfl(float x) {
    return __uint_as_float(__builtin_amdgcn_readfirstlane(__float_as_uint(x)));
}
__device__ __forceinline__ float rcpf(float x) { return __builtin_amdgcn_rcpf(x); }

// ---------------------------------------------------------------------------
// Kernel 1 (fused, r10-proven ~5us): per block = 8 rows x 32 h (256 threads).
//   y = x @ W_in^T + b_in ; Eh = exp2(c*y@W_h^T) ; Eo = exp2(c*y@W_o^T)
// ---------------------------------------------------------------------------
__global__ void __launch_bounds__(256) k_yho(
        const float* __restrict__ x,
        const float* __restrict__ W_in,
        const float* __restrict__ b_in,
        const float* __restrict__ W_h,
        const float* __restrict__ W_o,
        float* __restrict__ y,
        float* __restrict__ Eh,
        float* __restrict__ Eo) {
    __shared__ float xs[8][NIN_];   // 4 KB
    __shared__ float ys[8][H_];     // 1 KB
    const int t   = threadIdx.x;
    const int r   = t >> 5;              // local row 0..7
    const int hh  = t & 31;
    const int row = blockIdx.x * 8 + r;
    const int idx = row * H_ + hh;

    reinterpret_cast<float4*>(&xs[0][0])[t] =
        reinterpret_cast<const float4*>(x + (blockIdx.x * 8) * NIN_)[t];
    __syncthreads();

    {
        const float4* xl = reinterpret_cast<const float4*>(&xs[r][0]);
        const float4* w4 = reinterpret_cast<const float4*>(W_in + hh * NIN_);
        float a0 = b_in[hh], a1 = 0.f;
        #pragma unroll
        for (int k = 0; k < NIN_ / 8; ++k) {
            float4 xv0 = xl[2 * k],     wv0 = w4[2 * k];
            float4 xv1 = xl[2 * k + 1], wv1 = w4[2 * k + 1];
            a0 += xv0.x * wv0.x + xv0.y * wv0.y + xv0.z * wv0.z + xv0.w * wv0.w;
            a1 += xv1.x * wv1.x + xv1.y * wv1.y + xv1.z * wv1.z + xv1.w * wv1.w;
        }
        float acc = a0 + a1;
        ys[r][hh] = acc;
        y[idx] = acc;
    }
    __syncthreads();

    {
        const float4* y4  = reinterpret_cast<const float4*>(&ys[r][0]);
        const float4* wh4 = reinterpret_cast<const float4*>(W_h + hh * H_);
        const float4* wo4 = reinterpret_cast<const float4*>(W_o + hh * H_);
        float ah0 = 0.f, ah1 = 0.f, ao0 = 0.f, ao1 = 0.f;
        #pragma unroll
        for (int k = 0; k < H_ / 8; ++k) {
            float4 yv0 = y4[2 * k],     hv0 = wh4[2 * k],     ov0 = wo4[2 * k];
            float4 yv1 = y4[2 * k + 1], hv1 = wh4[2 * k + 1], ov1 = wo4[2 * k + 1];
            ah0 += yv0.x * hv0.x + yv0.y * hv0.y + yv0.z * hv0.z + yv0.w * hv0.w;
            ah1 += yv1.x * hv1.x + yv1.y * hv1.y + yv1.z * hv1.z + yv1.w * hv1.w;
            ao0 += yv0.x * ov0.x + yv0.y * ov0.y + yv0.z * ov0.z + yv0.w * ov0.w;
            ao1 += yv1.x * ov1.x + yv1.y * ov1.y + yv1.z * ov1.z + yv1.w * ov1.w;
        }
        Eh[idx] = __builtin_amdgcn_exp2f((ah0 + ah1) * C2L2E);
        Eo[idx] = __builtin_amdgcn_exp2f((ao0 + ao1) * C2L2E);
    }
}

// ---------------------------------------------------------------------------
// Kernel 2 (inverted e-loop, LDS-free score phase):
// block = 512 thd = 8 waves; 16 queries of one batch.
//   wave w: qg = w>>2 (queries qg*8..+8), ws = w&3 (j-slice 64*ws..+64).
//   lane owns j: Eo row in 32 VGPRs (global, once). Eh via UNIFORM scalar
//   loads (s_load; zero lane traffic). w2/vsum/va in SGPRs via rfl.
//   Fixed-shift softmax (no running max; r13-proven): s = sum exp2(E-va).
//   Cross-wave s-reduction via tiny sred + 1 barrier; att -> LDS; barrier;
//   ctx with coalesced y (j = n*8+js) + wave-local projection (r14 pattern).
// DS ops in score phase: ZERO. LDS total 18.5 KB.
// ---------------------------------------------------------------------------
__global__ void __launch_bounds__(512, 4) k_att(
        const float* __restrict__ y,
        const float* __restrict__ Eh,
        const float* __restrict__ Eo,
        const float* __restrict__ V,
        const float* __restrict__ W_out,
        const float* __restrict__ b_out,
        float* __restrict__ out) {
    __shared__ float att_p[16][T_];     // 16 KB
    __shared__ float sred[2][4][8];     // 256 B
    __shared__ float ctx_lds[16][H_];   // 2 KB

    const int t    = threadIdx.x;
    const int w    = __builtin_amdgcn_readfirstlane(t >> 6);  // wave 0..7
    const int lane = t & 63;
    const int qg   = w >> 2;            // query group 0/1
    const int ws   = w & 3;             // j-slice
    const int bb   = blockIdx.x >> 4;   // batch
    const int qb   = (blockIdx.x & 15) << 4;   // 16 queries/block
    const int j    = (ws << 6) + lane;

    // ---- Eo row -> VGPRs (issued first; 64 lines/wave, L2-hot) ----
    float4 eo[8];
    {
        const float4* ep = reinterpret_cast<const float4*>(Eo + (bb * T_ + j) * H_);
        #pragma unroll
        for (int p = 0; p < 8; ++p) eo[p] = ep[p];
    }

    // ---- V -> SGPRs (w2 = -2V), vsum/va scalars ----
    float w2[H_];
    float vsum = 0.f, va = 0.f;
    {
        const float4* V4 = reinterpret_cast<const float4*>(V);
        #pragma unroll
        for (int p = 0; p < 8; ++p) {
            float4 v = V4[p];
            w2[4 * p + 0] = rfl(v.x * -2.0f); w2[4 * p + 1] = rfl(v.y * -2.0f);
            w2[4 * p + 2] = rfl(v.z * -2.0f); w2[4 * p + 3] = rfl(v.w * -2.0f);
            vsum += (v.x + v.y) + (v.z + v.w);
            va   += (fabsf(v.x) + fabsf(v.y)) + (fabsf(v.z) + fabsf(v.w));
        }
        vsum = rfl(vsum); va = rfl(va);
    }

    // ---- E for 8 queries; Eh via uniform (scalar) loads, p-outer/q-inner
    //      so only 32 Eh scalars live at a time ----
    const int rq0 = bb * T_ + qb + (qg << 3);
    const float* ehbase = Eh + __builtin_amdgcn_readfirstlane(rq0) * H_;
    float Ea[8] = {0.f, 0.f, 0.f, 0.f, 0.f, 0.f, 0.f, 0.f};
    #pragma unroll
    for (int p = 0; p < 8; ++p) {
        #pragma unroll
        for (int q = 0; q < 8; ++q) {
            const float* hq4 = ehbase + q * H_ + 4 * p;   // uniform -> s_load
            float h0 = hq4[0], h1 = hq4[1], h2 = hq4[2], h3 = hq4[3];
            float e = Ea[q];
            e = fmaf(w2[4 * p + 0], rcpf(fmaf(h0, eo[p].x, 1.f)), e);
            e = fmaf(w2[4 * p + 1], rcpf(fmaf(h1, eo[p].y, 1.f)), e);
            e = fmaf(w2[4 * p + 2], rcpf(fmaf(h2, eo[p].z, 1.f)), e);
            e = fmaf(w2[4 * p + 3], rcpf(fmaf(h3, eo[p].w, 1.f)), e);
            Ea[q] = e;
        }
    }

    // ---- fixed-shift exp + per-wave s-partials (butterfly), sred ----
    const float soff = -va * L2E;
    float s[8];
    #pragma unroll
    for (int q = 0; q < 8; ++q) {
        Ea[q] += vsum;
        s[q] = __builtin_amdgcn_exp2f(fmaf(Ea[q], L2E, soff));
    }
    #pragma unroll
    for (int off = 1; off < 64; off <<= 1) {
        #pragma unroll
        for (int q = 0; q < 8; ++q)
            s[q] += __shfl_xor(s[q], off);
    }
    if (lane == 0) {
        float4 sa, sb;
        sa.x = s[0]; sa.y = s[1]; sa.z = s[2]; sa.w = s[3];
        sb.x = s[4]; sb.y = s[5]; sb.z = s[6]; sb.w = s[7];
        *reinterpret_cast<float4*>(&sred[qg][ws][0]) = sa;
        *reinterpret_cast<float4*>(&sred[qg][ws][4]) = sb;
    }
    __syncthreads();

    // ---- lse + att store (wave writes 64 consecutive floats per q) ----
    #pragma unroll
    for (int q = 0; q < 8; ++q) {
        float st = (sred[qg][0][q] + sred[qg][1][q])
                 + (sred[qg][2][q] + sred[qg][3][q]);
        float lse = va + __builtin_amdgcn_logf(st) * LN2;
        att_p[(qg << 3) + q][j] = Ea[q] - lse;
    }
    __syncthreads();

    // ---- ctx: wave w -> queries 2w, 2w+1; coalesced y (j = n*8+js) ----
    const int q0 = 2 * w, q1 = q0 + 1;
    {
        const int hq = lane & 7;
        const int js = lane >> 3;
        const float4* yb = reinterpret_cast<const float4*>(
            y + (bb * T_ + js) * H_ + hq * 4);
        float4 c0 = {0, 0, 0, 0}, c1 = {0, 0, 0, 0};
        #pragma unroll
        for (int n = 0; n < 32; ++n) {
            const int jj = n * 8 + js;
            float4 yv = yb[n * 8 * (H_ / 4)];     // wave covers 1KB contiguous
            float a0 = att_p[q0][jj];             // 8-addr broadcast
            float a1 = att_p[q1][jj];
            c0.x = fmaf(a0, yv.x, c0.x); c0.y = fmaf(a0, yv.y, c0.y);
            c0.z = fmaf(a0, yv.z, c0.z); c0.w = fmaf(a0, yv.w, c0.w);
            c1.x = fmaf(a1, yv.x, c1.x); c1.y = fmaf(a1, yv.y, c1.y);
            c1.z = fmaf(a1, yv.z, c1.z); c1.w = fmaf(a1, yv.w, c1.w);
        }
        #pragma unroll
        for (int off = 8; off < 64; off <<= 1) {
            c0.x += __shfl_xor(c0.x, off); c0.y += __shfl_xor(c0.y, off);
            c0.z += __shfl_xor(c0.z, off); c0.w += __shfl_xor(c0.w, off);
            c1.x += __shfl_xor(c1.x, off); c1.y += __shfl_xor(c1.y, off);
            c1.z += __shfl_xor(c1.z, off); c1.w += __shfl_xor(c1.w, off);
        }
        if (js == 0) {
            *reinterpret_cast<float4*>(&ctx_lds[q0][hq * 4]) = c0;
            *reinterpret_cast<float4*>(&ctx_lds[q1][hq * 4]) = c1;
        }
    }
    // ctx_lds consumed by the same wave (t>>5 in {2w, 2w+1}): no barrier.

    // ---- projection: thread = (oq = t>>5, ol = t&31), 4 oc each ----
    {
        const int oq = t >> 5;
        const int ol = t & 31;
        float4 cv[8];
        #pragma unroll
        for (int p = 0; p < 8; ++p)
            cv[p] = *reinterpret_cast<const float4*>(&ctx_lds[oq][4 * p]);
        float* orow = out + (bb * T_ + qb + oq) * NOUT_;
        #pragma unroll
        for (int u = 0; u < 4; ++u) {
            const int oc = ol + 32 * u;
            const float4* wp = reinterpret_cast<const float4*>(W_out + oc * H_);
            float p0 = b_out[oc], p1 = 0.f, p2 = 0.f, p3 = 0.f;
            #pragma unroll
            for (int p = 0; p < 8; p += 4) {
                float4 w0 = wp[p], w1 = wp[p + 1], w2_ = wp[p + 2], w3 = wp[p + 3];
                p0 += w0.x * cv[p].x + w0.y * cv[p].y + w0.z * cv[p].z + w0.w * cv[p].w;
                p1 += w1.x * cv[p+1].x + w1.y * cv[p+1].y + w1.z * cv[p+1].z + w1.w * cv[p+1].w;
                p2 += w2_.x * cv[p+2].x + w2_.y * cv[p+2].y + w2_.z * cv[p+2].z + w2_.w * cv[p+2].w;
                p3 += w3.x * cv[p+3].x + w3.y * cv[p+3].y + w3.z * cv[p+3].z + w3.w * cv[p+3].w;
            }
            orow[oc] = (p0 + p1) + (p2 + p3);
        }
    }
}

// ---------------------------------------------------------------------------
extern "C" void kernel_launch(void* const* d_in, const int* in_sizes, int n_in,
                              void* d_out, int out_size, void* d_ws, size_t ws_size,
                              hipStream_t stream) {
    const float* x     = (const float*)d_in[0];
    const float* W_in  = (const float*)d_in[1];
    const float* b_in  = (const float*)d_in[2];
    const float* W_h   = (const float*)d_in[3];
    const float* W_o   = (const float*)d_in[4];
    const float* V     = (const float*)d_in[5];
    const float* W_out = (const float*)d_in[6];
    const float* b_out = (const float*)d_in[7];
    float* out = (float*)d_out;

    // workspace layout: y | Eh | Eo  (each R_*H_ floats = 1 MB)
    float* y  = (float*)d_ws;
    float* Eh = y + R_ * H_;
    float* Eo = Eh + R_ * H_;

    k_yho<<<R_ / 8, 256, 0, stream>>>(x, W_in, b_in, W_h, W_o, y, Eh, Eo);
    k_att<<<R_ / 16, 512, 0, stream>>>(y, Eh, Eo, V, W_out, b_out, out);
}